// Round 4
// baseline (1365.237 us; speedup 1.0000x reference)
//
#include <hip/hip_runtime.h>
#include <stdint.h>

typedef unsigned short u16;
typedef __bf16 bf16x8 __attribute__((ext_vector_type(8)));
typedef float f32x4 __attribute__((ext_vector_type(4)));

#define MOD6  6144

__device__ __forceinline__ float b2f(unsigned int u) {
    union { unsigned int i; float f; } z; z.i = u << 16; return z.f;
}
__device__ __forceinline__ u16 f2b(float f) {
    union { float f; unsigned int i; } z; z.f = f;
    unsigned int i = z.i;
    return (u16)((i + 0x7fffu + ((i >> 16) & 1u)) >> 16);
}
union U4 { uint4 u; u16 s[8]; };
union U2 { uint2 u; u16 s[4]; };

__device__ __forceinline__ void unpack8(uint4 v, float* f) {
    f[0] = b2f(v.x & 0xffffu); f[1] = b2f(v.x >> 16);
    f[2] = b2f(v.y & 0xffffu); f[3] = b2f(v.y >> 16);
    f[4] = b2f(v.z & 0xffffu); f[5] = b2f(v.z >> 16);
    f[6] = b2f(v.w & 0xffffu); f[7] = b2f(v.w >> 16);
}

// dual-dtype external-input readers (isbf: 1 = bf16, 0 = f32)
__device__ __forceinline__ float ldf(const void* p, size_t i, int isbf) {
    if (isbf) return b2f(((const u16*)p)[i]);
    return ((const float*)p)[i];
}
__device__ __forceinline__ void load4(const void* p, size_t i, int isbf, float* v) {
    if (isbf) {
        U2 t; t.u = *(const uint2*)((const u16*)p + i);
#pragma unroll
        for (int e = 0; e < 4; e++) v[e] = b2f(t.s[e]);
    } else {
        float4 f = *(const float4*)((const float*)p + i);
        v[0] = f.x; v[1] = f.y; v[2] = f.z; v[3] = f.w;
    }
}

// ------------------------------------------------ dtype detector
// w_ln1 is all-ones: bf16 pair word = 0x3F803F80, f32 word = 0x3F800000.
__global__ void detect_dtype(const unsigned int* __restrict__ w, int* __restrict__ flag) {
    if (threadIdx.x == 0 && blockIdx.x == 0)
        *flag = (w[0] == 0x3F803F80u) ? 1 : 0;
}

// ------------------------------------------------ transpose (K,N) ext -> bf16 (N,K)
__global__ void transpose_any(const void* __restrict__ in, u16* __restrict__ out,
                              int K, int N, const int* __restrict__ flag) {
    const int isbf = *flag;
    __shared__ u16 tile[64][66];
    const int ntn = N >> 6;
    const int k0 = (blockIdx.x / ntn) << 6;
    const int n0 = (blockIdx.x % ntn) << 6;
    const int tid = threadIdx.x;
    const int r = tid >> 3;          // 0..31
    const int c = (tid & 7) * 8;     // 0..56
#pragma unroll
    for (int rr = 0; rr < 64; rr += 32) {
        const size_t base = (size_t)(k0 + r + rr) * N + n0 + c;
        u16* t = &tile[r + rr][c];
        if (isbf) {
            U4 v; v.u = *(const uint4*)((const u16*)in + base);
#pragma unroll
            for (int e = 0; e < 8; e++) t[e] = v.s[e];
        } else {
            float4 a = *(const float4*)((const float*)in + base);
            float4 b = *(const float4*)((const float*)in + base + 4);
            t[0] = f2b(a.x); t[1] = f2b(a.y); t[2] = f2b(a.z); t[3] = f2b(a.w);
            t[4] = f2b(b.x); t[5] = f2b(b.y); t[6] = f2b(b.z); t[7] = f2b(b.w);
        }
    }
    __syncthreads();
#pragma unroll
    for (int rr = 0; rr < 64; rr += 32) {
        U4 v;
#pragma unroll
        for (int e = 0; e < 8; e++) v.s[e] = tile[c + e][r + rr];
        *(uint4*)&out[(size_t)(n0 + r + rr) * K + k0 + c] = v.u;
    }
}

// ------------------------------------------------ adaLN modulation -> f32
__global__ void ada_kernel(const void* __restrict__ c, const void* __restrict__ w_ada,
                           const void* __restrict__ b_ada, float* __restrict__ mod,
                           const int* __restrict__ flag) {
    const int isbf = *flag;
    const int g = blockIdx.x * 256 + threadIdx.x;   // 0..24575
    const int b = g / MOD6, n = g % MOD6;
    float acc = 0.f;
    if (isbf) {
        const u16* cr = (const u16*)c + b * 1024;
        const u16* w = (const u16*)w_ada;
#pragma unroll 4
        for (int k = 0; k < 1024; k++)
            acc += b2f(cr[k]) * b2f(w[(size_t)k * MOD6 + n]);
    } else {
        const float* cr = (const float*)c + b * 1024;
        const float* w = (const float*)w_ada;
#pragma unroll 4
        for (int k = 0; k < 1024; k++)
            acc += cr[k] * w[(size_t)k * MOD6 + n];
    }
    mod[g] = acc + ldf(b_ada, n, isbf);
}

// ------------------------------------------------ LN + modulate -> bf16
__global__ void ln_mod_kernel(const void* __restrict__ x, const void* __restrict__ w,
                              const float* __restrict__ mod, int shift_off,
                              int scale_off, u16* __restrict__ out,
                              const int* __restrict__ flag, int x_is_f32) {
    const int isbf = *flag;
    const int xb = x_is_f32 ? 0 : isbf;
    const int tk = blockIdx.x;
    const int b = tk >> 10;
    const int tid = threadIdx.x;
    float v[4];
    load4(x, (size_t)tk * 1024 + tid * 4, xb, v);
    float s = v[0] + v[1] + v[2] + v[3];
    float ss = v[0]*v[0] + v[1]*v[1] + v[2]*v[2] + v[3]*v[3];
#pragma unroll
    for (int off = 1; off < 64; off <<= 1) {
        s  += __shfl_xor(s, off);
        ss += __shfl_xor(ss, off);
    }
    __shared__ float ls[4], lss[4];
    if ((tid & 63) == 0) { ls[tid >> 6] = s; lss[tid >> 6] = ss; }
    __syncthreads();
    s  = ls[0] + ls[1] + ls[2] + ls[3];
    ss = lss[0] + lss[1] + lss[2] + lss[3];
    const float mu  = s * (1.f / 1024.f);
    const float var = ss * (1.f / 1024.f) - mu * mu;
    const float rstd = rsqrtf(var + 1e-5f);
    float wv[4];
    load4(w, (size_t)tid * 4, isbf, wv);
    const float* mb = mod + (size_t)b * MOD6;
    U2 o;
#pragma unroll
    for (int e = 0; e < 4; e++) {
        const int col = tid * 4 + e;
        float n = (v[e] - mu) * rstd * wv[e];
        o.s[e] = f2b(n * (1.f + mb[scale_off + col]) + mb[shift_off + col]);
    }
    *(uint2*)(out + (size_t)tk * 1024 + tid * 4) = o.u;
}

// ------------------------------------------------ GEMM  C = A @ Bt^T (+epilogue)
#define EPI_STORE 0
#define EPI_RES_GATE 1        // f32 out: res_ext(dual) + gate*v
#define EPI_GELU_BIAS 2       // bf16 out: gelu(v + bias_ext)
#define EPI_RES_GATE_BIAS 3   // f32 out (d_out!): res_f32 + gate*(v + bias_ext)

template <int EPI>
__launch_bounds__(256, 2)
__global__ void gemm_bt(const u16* __restrict__ A, const u16* __restrict__ Bt,
                        void* __restrict__ Cv, int M, int N, int K,
                        const void* __restrict__ res, const float* __restrict__ gate,
                        const void* __restrict__ bias, const int* __restrict__ flag) {
    __shared__ __align__(16) u16 sA[128 * 40];
    __shared__ __align__(16) u16 sB[128 * 40];
    const int isbf = flag ? *flag : 0;
    const int tid = threadIdx.x;
    const int lane = tid & 63;
    const int w = tid >> 6;
    const int wm = w >> 1, wn = w & 1;
    const int c16 = lane & 15, quad = lane >> 4;
    const int m0 = blockIdx.y * 128, n0 = blockIdx.x * 128;

    const int lr = tid >> 1;           // 0..127
    const int lc = (tid & 1) * 16;     // 0 / 16

    const u16* gA = A + (size_t)(m0 + lr) * K + lc;
    const u16* gB = Bt + (size_t)(n0 + lr) * K + lc;

    f32x4 acc[4][4];
#pragma unroll
    for (int i = 0; i < 4; i++)
#pragma unroll
        for (int j = 0; j < 4; j++) acc[i][j] = (f32x4){0.f, 0.f, 0.f, 0.f};

    uint4 ra0 = *(const uint4*)(gA);
    uint4 ra1 = *(const uint4*)(gA + 8);
    uint4 rb0 = *(const uint4*)(gB);
    uint4 rb1 = *(const uint4*)(gB + 8);

#pragma unroll 1
    for (int kt = 0; kt < K; kt += 32) {
        __syncthreads();
        *(uint4*)&sA[lr * 40 + lc]     = ra0;
        *(uint4*)&sA[lr * 40 + lc + 8] = ra1;
        *(uint4*)&sB[lr * 40 + lc]     = rb0;
        *(uint4*)&sB[lr * 40 + lc + 8] = rb1;
        __syncthreads();
        if (kt + 32 < K) {
            ra0 = *(const uint4*)(gA + kt + 32);
            ra1 = *(const uint4*)(gA + kt + 40);
            rb0 = *(const uint4*)(gB + kt + 32);
            rb1 = *(const uint4*)(gB + kt + 40);
        }
        bf16x8 af[4], bfr[4];
#pragma unroll
        for (int i = 0; i < 4; i++)
            af[i] = *(const bf16x8*)&sA[(64 * wm + 16 * i + c16) * 40 + 8 * quad];
#pragma unroll
        for (int j = 0; j < 4; j++)
            bfr[j] = *(const bf16x8*)&sB[(64 * wn + 16 * j + c16) * 40 + 8 * quad];
#pragma unroll
        for (int i = 0; i < 4; i++)
#pragma unroll
            for (int j = 0; j < 4; j++)
                acc[i][j] = __builtin_amdgcn_mfma_f32_16x16x32_bf16(
                    af[i], bfr[j], acc[i][j], 0, 0, 0);
    }

#pragma unroll
    for (int i = 0; i < 4; i++) {
#pragma unroll
        for (int r = 0; r < 4; r++) {
            const int row = m0 + 64 * wm + 16 * i + 4 * quad + r;
            const int b = row >> 10;
#pragma unroll
            for (int j = 0; j < 4; j++) {
                const int col = n0 + 64 * wn + 16 * j + c16;
                float v = acc[i][j][r];
                if constexpr (EPI == EPI_GELU_BIAS) {
                    v += ldf(bias, col, isbf);
                    const float u = 0.7978845608f * (v + 0.044715f * v * v * v);
                    const float e = __expf(2.f * u);
                    const float t = 1.f - 2.f / (e + 1.f);   // tanh(u), inf-safe
                    v = 0.5f * v * (1.f + t);
                } else if constexpr (EPI == EPI_RES_GATE) {
                    v = ldf(res, (size_t)row * N + col, isbf)
                        + gate[(size_t)b * MOD6 + col] * v;
                } else if constexpr (EPI == EPI_RES_GATE_BIAS) {
                    v += ldf(bias, col, isbf);
                    v = ((const float*)res)[(size_t)row * N + col]
                        + gate[(size_t)b * MOD6 + col] * v;
                }
                if constexpr (EPI == EPI_RES_GATE || EPI == EPI_RES_GATE_BIAS) {
                    ((float*)Cv)[(size_t)row * N + col] = v;   // f32 (x2 / d_out)
                } else {
                    ((u16*)Cv)[(size_t)row * N + col] = f2b(v);
                }
            }
        }
    }
}

// ------------------------------------------------ RoPE in-place on qkv (bf16)
__global__ void rope_kernel(u16* __restrict__ qkv, const void* __restrict__ cosb,
                            const void* __restrict__ sinb, const int* __restrict__ flag) {
    const int isbf = *flag;
    const int g = blockIdx.x * 256 + threadIdx.x;  // 524288
    const int q8 = g & 7;
    const int h = (g >> 3) & 15;
    const int tk = g >> 7;
    const int s = tk & 1023;
    const int d = q8 * 4;
    u16* row = qkv + (size_t)tk * 3072;

    float c4[4], s4[4];
    load4(cosb, (size_t)s * 32 + d, isbf, c4);
    load4(sinb, (size_t)s * 32 + d, isbf, s4);

#pragma unroll
    for (int which = 0; which < 2; which++) {   // q then k
        u16* p1 = row + which * 1024 + h * 64 + d;
        u16* p2 = p1 + 32;
        U2 t1, t2;
        t1.u = *(const uint2*)p1;
        t2.u = *(const uint2*)p2;
        U2 o1, o2;
#pragma unroll
        for (int e = 0; e < 4; e++) {
            const float a = b2f(t1.s[e]), bb = b2f(t2.s[e]);
            o1.s[e] = f2b(a * c4[e] - bb * s4[e]);
            o2.s[e] = f2b(bb * c4[e] + a * s4[e]);
        }
        *(uint2*)p1 = o1.u;
        *(uint2*)p2 = o2.u;
    }
}

// ------------------------------------------------ attention (reads qkv in-place)
__launch_bounds__(256, 2)
__global__ void attn_kernel(const u16* __restrict__ qkv, u16* __restrict__ o_out) {
    __shared__ __align__(16) float sK[64 * 68];
    __shared__ __align__(16) float sV[64 * 68];
    const int bh = blockIdx.x >> 2;   // 0..63
    const int qt = blockIdx.x & 3;
    const int tid = threadIdx.x;
    const int qi = qt * 256 + tid;
    const int b = bh >> 4, h = bh & 15;

    float q[64];
    {
        const uint4* qp = (const uint4*)(qkv + (size_t)(b * 1024 + qi) * 3072 + h * 64);
#pragma unroll
        for (int c = 0; c < 8; c++) { uint4 r = qp[c]; unpack8(r, &q[c * 8]); }
    }
    float o[64];
#pragma unroll
    for (int d = 0; d < 64; d++) o[d] = 0.f;
    float mI = -1e30f, lI = 0.f;

    const int sr = tid >> 2;
    const int scc = (tid & 3) * 16;

#pragma unroll 1
    for (int kt = 0; kt < 1024; kt += 64) {
        __syncthreads();
        {
            const u16* kp = qkv + (size_t)(b * 1024 + kt + sr) * 3072 + 1024 + h * 64 + scc;
            const u16* vp = kp + 1024;
            uint4 a0 = *(const uint4*)kp, a1 = *(const uint4*)(kp + 8);
            uint4 c0 = *(const uint4*)vp, c1 = *(const uint4*)(vp + 8);
            float fk[16], fv[16];
            unpack8(a0, fk); unpack8(a1, fk + 8);
            unpack8(c0, fv); unpack8(c1, fv + 8);
            float4* dK = (float4*)&sK[sr * 68 + scc];
            float4* dV = (float4*)&sV[sr * 68 + scc];
#pragma unroll
            for (int e = 0; e < 4; e++) {
                dK[e] = make_float4(fk[4*e], fk[4*e+1], fk[4*e+2], fk[4*e+3]);
                dV[e] = make_float4(fv[4*e], fv[4*e+1], fv[4*e+2], fv[4*e+3]);
            }
        }
        __syncthreads();
#pragma unroll 1
        for (int jt = 0; jt < 4; jt++) {
            float sc[16];
#pragma unroll
            for (int jj = 0; jj < 16; jj++) {
                const float4* k4 = (const float4*)&sK[(jt * 16 + jj) * 68];
                float a0 = 0.f, a1 = 0.f, a2 = 0.f, a3 = 0.f;
#pragma unroll
                for (int d4 = 0; d4 < 16; d4++) {
                    float4 kk = k4[d4];
                    a0 += q[4*d4+0] * kk.x; a1 += q[4*d4+1] * kk.y;
                    a2 += q[4*d4+2] * kk.z; a3 += q[4*d4+3] * kk.w;
                }
                sc[jj] = ((a0 + a1) + (a2 + a3)) * 0.125f;
            }
            float tm = sc[0];
#pragma unroll
            for (int jj = 1; jj < 16; jj++) tm = fmaxf(tm, sc[jj]);
            const float mNew = fmaxf(mI, tm);
            const float alpha = __expf(mI - mNew);
            lI *= alpha;
#pragma unroll
            for (int d = 0; d < 64; d++) o[d] *= alpha;
            mI = mNew;
#pragma unroll
            for (int jj = 0; jj < 16; jj++) {
                const float p = __expf(sc[jj] - mI);
                lI += p;
                const float4* v4 = (const float4*)&sV[(jt * 16 + jj) * 68];
#pragma unroll
                for (int d4 = 0; d4 < 16; d4++) {
                    float4 vv = v4[d4];
                    o[4*d4+0] += p * vv.x; o[4*d4+1] += p * vv.y;
                    o[4*d4+2] += p * vv.z; o[4*d4+3] += p * vv.w;
                }
            }
        }
    }
    const float inv = 1.f / lI;
    u16* op = o_out + (size_t)(b * 1024 + qi) * 1024 + h * 64;
#pragma unroll
    for (int g8 = 0; g8 < 8; g8++) {
        U4 pk;
#pragma unroll
        for (int e = 0; e < 8; e++) pk.s[e] = f2b(o[g8 * 8 + e] * inv);
        *(uint4*)(op + g8 * 8) = pk.u;
    }
}

// ------------------------------------------------ launch
extern "C" void kernel_launch(void* const* d_in, const int* in_sizes, int n_in,
                              void* d_out, int out_size, void* d_ws, size_t ws_size,
                              hipStream_t stream) {
    (void)in_sizes; (void)n_in; (void)out_size; (void)ws_size;
    const void* x      = d_in[0];
    const void* cosb   = d_in[1];
    const void* sinb   = d_in[2];
    const void* c      = d_in[3];
    const void* w_ln1  = d_in[4];
    const void* w_ln2  = d_in[5];
    const void* w_qkv  = d_in[6];
    const void* w_attn = d_in[7];
    const void* w_mlp1 = d_in[8];
    const void* b_mlp1 = d_in[9];
    const void* w_mlp2 = d_in[10];
    const void* b_mlp2 = d_in[11];
    const void* w_ada  = d_in[12];
    const void* b_ada  = d_in[13];
    char* ws = (char*)d_ws;

    u16*   wT_qkv  = (u16*)(ws + 0);          // 3072x1024 bf16
    u16*   wT_attn = (u16*)(ws + 6291456);    // 1024x1024 bf16
    u16*   wT_mlp1 = (u16*)(ws + 8388608);    // 4096x1024 bf16
    u16*   wT_mlp2 = (u16*)(ws + 16777216);   // 1024x4096 bf16
    float* mod     = (float*)(ws + 25165824); // 4x6144 f32
    u16*   hbuf    = (u16*)(ws + 25264128);   // h -> o -> h2 (4096x1024 bf16)
    u16*   big     = (u16*)(ws + 33652736);   // qkv (4096x3072) -> m1 (4096x4096) bf16
    float* x2      = (float*)(ws + 67207168); // 4096x1024 f32
    int*   flag    = (int*)(ws + 83984384);   // dtype flag
    // total: 83,984,388 bytes

    detect_dtype<<<1, 64, 0, stream>>>((const unsigned int*)w_ln1, flag);
    transpose_any<<<dim3(16 * 48), 256, 0, stream>>>(w_qkv, wT_qkv, 1024, 3072, flag);
    transpose_any<<<dim3(16 * 16), 256, 0, stream>>>(w_attn, wT_attn, 1024, 1024, flag);
    transpose_any<<<dim3(16 * 64), 256, 0, stream>>>(w_mlp1, wT_mlp1, 1024, 4096, flag);
    transpose_any<<<dim3(64 * 16), 256, 0, stream>>>(w_mlp2, wT_mlp2, 4096, 1024, flag);
    ada_kernel<<<96, 256, 0, stream>>>(c, w_ada, b_ada, mod, flag);
    ln_mod_kernel<<<4096, 256, 0, stream>>>(x, w_ln1, mod, 0, 1024, hbuf, flag, 0);
    gemm_bt<EPI_STORE><<<dim3(24, 32), 256, 0, stream>>>(
        hbuf, wT_qkv, big, 4096, 3072, 1024, nullptr, nullptr, nullptr, flag);
    rope_kernel<<<2048, 256, 0, stream>>>(big, cosb, sinb, flag);
    attn_kernel<<<256, 256, 0, stream>>>(big, hbuf);
    gemm_bt<EPI_RES_GATE><<<dim3(8, 32), 256, 0, stream>>>(
        hbuf, wT_attn, x2, 4096, 1024, 1024, x, mod + 2048, nullptr, flag);
    ln_mod_kernel<<<4096, 256, 0, stream>>>(x2, w_ln2, mod, 3072, 4096, hbuf, flag, 1);
    gemm_bt<EPI_GELU_BIAS><<<dim3(32, 32), 256, 0, stream>>>(
        hbuf, wT_mlp1, big, 4096, 4096, 1024, nullptr, nullptr, b_mlp1, flag);
    gemm_bt<EPI_RES_GATE_BIAS><<<dim3(8, 32), 256, 0, stream>>>(
        big, wT_mlp2, (float*)d_out, 4096, 1024, 4096, x2, mod + 5120, b_mlp2, flag);
}

// Round 5
// 569.683 us; speedup vs baseline: 2.3965x; 2.3965x over previous
//
#include <hip/hip_runtime.h>
#include <stdint.h>

typedef unsigned short u16;
typedef __bf16 bf16x8 __attribute__((ext_vector_type(8)));
typedef float f32x4 __attribute__((ext_vector_type(4)));

#define MOD6  6144

__device__ __forceinline__ float b2f(unsigned int u) {
    union { unsigned int i; float f; } z; z.i = u << 16; return z.f;
}
__device__ __forceinline__ u16 f2b(float f) {
    union { float f; unsigned int i; } z; z.f = f;
    unsigned int i = z.i;
    return (u16)((i + 0x7fffu + ((i >> 16) & 1u)) >> 16);
}
union U4 { uint4 u; u16 s[8]; };
union U2 { uint2 u; u16 s[4]; };
union B8 { bf16x8 v; unsigned int w[4]; };

// dual-dtype external-input readers (isbf: 1 = bf16, 0 = f32)
__device__ __forceinline__ float ldf(const void* p, size_t i, int isbf) {
    if (isbf) return b2f(((const u16*)p)[i]);
    return ((const float*)p)[i];
}
__device__ __forceinline__ void load4(const void* p, size_t i, int isbf, float* v) {
    if (isbf) {
        U2 t; t.u = *(const uint2*)((const u16*)p + i);
#pragma unroll
        for (int e = 0; e < 4; e++) v[e] = b2f(t.s[e]);
    } else {
        float4 f = *(const float4*)((const float*)p + i);
        v[0] = f.x; v[1] = f.y; v[2] = f.z; v[3] = f.w;
    }
}

// ------------------------------------------------ dtype detector
__global__ void detect_dtype(const unsigned int* __restrict__ w, int* __restrict__ flag) {
    if (threadIdx.x == 0 && blockIdx.x == 0)
        *flag = (w[0] == 0x3F803F80u) ? 1 : 0;
}

// ------------------------------------------------ transpose (K,N) ext -> bf16 (N,K)
__global__ void transpose_any(const void* __restrict__ in, u16* __restrict__ out,
                              int K, int N, const int* __restrict__ flag) {
    const int isbf = *flag;
    __shared__ u16 tile[64][66];
    const int ntn = N >> 6;
    const int k0 = (blockIdx.x / ntn) << 6;
    const int n0 = (blockIdx.x % ntn) << 6;
    const int tid = threadIdx.x;
    const int r = tid >> 3;          // 0..31
    const int c = (tid & 7) * 8;     // 0..56
#pragma unroll
    for (int rr = 0; rr < 64; rr += 32) {
        const size_t base = (size_t)(k0 + r + rr) * N + n0 + c;
        u16* t = &tile[r + rr][c];
        if (isbf) {
            U4 v; v.u = *(const uint4*)((const u16*)in + base);
#pragma unroll
            for (int e = 0; e < 8; e++) t[e] = v.s[e];
        } else {
            float4 a = *(const float4*)((const float*)in + base);
            float4 b = *(const float4*)((const float*)in + base + 4);
            t[0] = f2b(a.x); t[1] = f2b(a.y); t[2] = f2b(a.z); t[3] = f2b(a.w);
            t[4] = f2b(b.x); t[5] = f2b(b.y); t[6] = f2b(b.z); t[7] = f2b(b.w);
        }
    }
    __syncthreads();
#pragma unroll
    for (int rr = 0; rr < 64; rr += 32) {
        U4 v;
#pragma unroll
        for (int e = 0; e < 8; e++) v.s[e] = tile[c + e][r + rr];
        *(uint4*)&out[(size_t)(n0 + r + rr) * K + k0 + c] = v.u;
    }
}

// ------------------------------------------------ adaLN modulation -> f32
__global__ void ada_kernel(const void* __restrict__ c, const void* __restrict__ w_ada,
                           const void* __restrict__ b_ada, float* __restrict__ mod,
                           const int* __restrict__ flag) {
    const int isbf = *flag;
    const int g = blockIdx.x * 256 + threadIdx.x;   // 0..24575
    const int b = g / MOD6, n = g % MOD6;
    float acc = 0.f;
    if (isbf) {
        const u16* cr = (const u16*)c + b * 1024;
        const u16* w = (const u16*)w_ada;
#pragma unroll 4
        for (int k = 0; k < 1024; k++)
            acc += b2f(cr[k]) * b2f(w[(size_t)k * MOD6 + n]);
    } else {
        const float* cr = (const float*)c + b * 1024;
        const float* w = (const float*)w_ada;
#pragma unroll 4
        for (int k = 0; k < 1024; k++)
            acc += cr[k] * w[(size_t)k * MOD6 + n];
    }
    mod[g] = acc + ldf(b_ada, n, isbf);
}

// ------------------------------------------------ LN + modulate -> bf16
__global__ void ln_mod_kernel(const void* __restrict__ x, const void* __restrict__ w,
                              const float* __restrict__ mod, int shift_off,
                              int scale_off, u16* __restrict__ out,
                              const int* __restrict__ flag, int x_is_f32) {
    const int isbf = *flag;
    const int xb = x_is_f32 ? 0 : isbf;
    const int tk = blockIdx.x;
    const int b = tk >> 10;
    const int tid = threadIdx.x;
    float v[4];
    load4(x, (size_t)tk * 1024 + tid * 4, xb, v);
    float s = v[0] + v[1] + v[2] + v[3];
    float ss = v[0]*v[0] + v[1]*v[1] + v[2]*v[2] + v[3]*v[3];
#pragma unroll
    for (int off = 1; off < 64; off <<= 1) {
        s  += __shfl_xor(s, off);
        ss += __shfl_xor(ss, off);
    }
    __shared__ float ls[4], lss[4];
    if ((tid & 63) == 0) { ls[tid >> 6] = s; lss[tid >> 6] = ss; }
    __syncthreads();
    s  = ls[0] + ls[1] + ls[2] + ls[3];
    ss = lss[0] + lss[1] + lss[2] + lss[3];
    const float mu  = s * (1.f / 1024.f);
    const float var = ss * (1.f / 1024.f) - mu * mu;
    const float rstd = rsqrtf(var + 1e-5f);
    float wv[4];
    load4(w, (size_t)tid * 4, isbf, wv);
    const float* mb = mod + (size_t)b * MOD6;
    U2 o;
#pragma unroll
    for (int e = 0; e < 4; e++) {
        const int col = tid * 4 + e;
        float n = (v[e] - mu) * rstd * wv[e];
        o.s[e] = f2b(n * (1.f + mb[scale_off + col]) + mb[shift_off + col]);
    }
    *(uint2*)(out + (size_t)tk * 1024 + tid * 4) = o.u;
}

// ------------------------------------------------ GEMM  C = A @ Bt^T (+epilogue)
#define EPI_STORE 0
#define EPI_RES_GATE 1        // f32 out: res_ext(dual) + gate*v
#define EPI_GELU_BIAS 2       // bf16 out: gelu(v + bias_ext)
#define EPI_RES_GATE_BIAS 3   // f32 out (d_out): res_f32 + gate*(v + bias_ext)

template <int EPI>
__launch_bounds__(256, 2)
__global__ void gemm_bt(const u16* __restrict__ A, const u16* __restrict__ Bt,
                        void* __restrict__ Cv, int M, int N, int K,
                        const void* __restrict__ res, const float* __restrict__ gate,
                        const void* __restrict__ bias, const int* __restrict__ flag) {
    __shared__ __align__(16) u16 sA[128 * 40];
    __shared__ __align__(16) u16 sB[128 * 40];
    const int isbf = flag ? *flag : 0;
    const int tid = threadIdx.x;
    const int lane = tid & 63;
    const int w = tid >> 6;
    const int wm = w >> 1, wn = w & 1;
    const int c16 = lane & 15, quad = lane >> 4;
    const int m0 = blockIdx.y * 128, n0 = blockIdx.x * 128;

    const int lr = tid >> 1;           // 0..127
    const int lc = (tid & 1) * 16;     // 0 / 16

    const u16* gA = A + (size_t)(m0 + lr) * K + lc;
    const u16* gB = Bt + (size_t)(n0 + lr) * K + lc;

    f32x4 acc[4][4];
#pragma unroll
    for (int i = 0; i < 4; i++)
#pragma unroll
        for (int j = 0; j < 4; j++) acc[i][j] = (f32x4){0.f, 0.f, 0.f, 0.f};

    uint4 ra0 = *(const uint4*)(gA);
    uint4 ra1 = *(const uint4*)(gA + 8);
    uint4 rb0 = *(const uint4*)(gB);
    uint4 rb1 = *(const uint4*)(gB + 8);

#pragma unroll 1
    for (int kt = 0; kt < K; kt += 32) {
        __syncthreads();
        *(uint4*)&sA[lr * 40 + lc]     = ra0;
        *(uint4*)&sA[lr * 40 + lc + 8] = ra1;
        *(uint4*)&sB[lr * 40 + lc]     = rb0;
        *(uint4*)&sB[lr * 40 + lc + 8] = rb1;
        __syncthreads();
        if (kt + 32 < K) {
            ra0 = *(const uint4*)(gA + kt + 32);
            ra1 = *(const uint4*)(gA + kt + 40);
            rb0 = *(const uint4*)(gB + kt + 32);
            rb1 = *(const uint4*)(gB + kt + 40);
        }
        bf16x8 af[4], bfr[4];
#pragma unroll
        for (int i = 0; i < 4; i++)
            af[i] = *(const bf16x8*)&sA[(64 * wm + 16 * i + c16) * 40 + 8 * quad];
#pragma unroll
        for (int j = 0; j < 4; j++)
            bfr[j] = *(const bf16x8*)&sB[(64 * wn + 16 * j + c16) * 40 + 8 * quad];
#pragma unroll
        for (int i = 0; i < 4; i++)
#pragma unroll
            for (int j = 0; j < 4; j++)
                acc[i][j] = __builtin_amdgcn_mfma_f32_16x16x32_bf16(
                    af[i], bfr[j], acc[i][j], 0, 0, 0);
    }

#pragma unroll
    for (int i = 0; i < 4; i++) {
#pragma unroll
        for (int r = 0; r < 4; r++) {
            const int row = m0 + 64 * wm + 16 * i + 4 * quad + r;
            const int b = row >> 10;
#pragma unroll
            for (int j = 0; j < 4; j++) {
                const int col = n0 + 64 * wn + 16 * j + c16;
                float v = acc[i][j][r];
                if constexpr (EPI == EPI_GELU_BIAS) {
                    v += ldf(bias, col, isbf);
                    const float u = 0.7978845608f * (v + 0.044715f * v * v * v);
                    const float e = __expf(2.f * u);
                    const float t = 1.f - 2.f / (e + 1.f);   // tanh(u), inf-safe
                    v = 0.5f * v * (1.f + t);
                } else if constexpr (EPI == EPI_RES_GATE) {
                    v = ldf(res, (size_t)row * N + col, isbf)
                        + gate[(size_t)b * MOD6 + col] * v;
                } else if constexpr (EPI == EPI_RES_GATE_BIAS) {
                    v += ldf(bias, col, isbf);
                    v = ((const float*)res)[(size_t)row * N + col]
                        + gate[(size_t)b * MOD6 + col] * v;
                }
                if constexpr (EPI == EPI_RES_GATE || EPI == EPI_RES_GATE_BIAS) {
                    ((float*)Cv)[(size_t)row * N + col] = v;
                } else {
                    ((u16*)Cv)[(size_t)row * N + col] = f2b(v);
                }
            }
        }
    }
}

// ------------------------------------------------ RoPE in-place on qkv (bf16)
__global__ void rope_kernel(u16* __restrict__ qkv, const void* __restrict__ cosb,
                            const void* __restrict__ sinb, const int* __restrict__ flag) {
    const int isbf = *flag;
    const int g = blockIdx.x * 256 + threadIdx.x;  // 524288
    const int q8 = g & 7;
    const int h = (g >> 3) & 15;
    const int tk = g >> 7;
    const int s = tk & 1023;
    const int d = q8 * 4;
    u16* row = qkv + (size_t)tk * 3072;

    float c4[4], s4[4];
    load4(cosb, (size_t)s * 32 + d, isbf, c4);
    load4(sinb, (size_t)s * 32 + d, isbf, s4);

#pragma unroll
    for (int which = 0; which < 2; which++) {   // q then k
        u16* p1 = row + which * 1024 + h * 64 + d;
        u16* p2 = p1 + 32;
        U2 t1, t2;
        t1.u = *(const uint2*)p1;
        t2.u = *(const uint2*)p2;
        U2 o1, o2;
#pragma unroll
        for (int e = 0; e < 4; e++) {
            const float a = b2f(t1.s[e]), bb = b2f(t2.s[e]);
            o1.s[e] = f2b(a * c4[e] - bb * s4[e]);
            o2.s[e] = f2b(bb * c4[e] + a * s4[e]);
        }
        *(uint2*)p1 = o1.u;
        *(uint2*)p2 = o2.u;
    }
}

// ------------------------------------------------ MFMA flash attention
// grid: bh*16 + qt. Block: 4 waves; wave w owns q rows [qt*64+w*16, +16).
// S^T = K·Q^T (A=K, B=Q^T), online softmax per lane (q = lane&15, stats
// reduced over quads), O^T = V^T·P^T with P lane-permuted into B-layout.
__launch_bounds__(256, 4)
__global__ void attn_mfma(const u16* __restrict__ qkv, u16* __restrict__ o_out) {
    __shared__ __align__(16) u16 sK[64 * 72];    // keys x dims, pad 72
    __shared__ __align__(16) u16 sVt[64 * 72];   // dims x keys, pad 72
    const int bh = blockIdx.x >> 4;
    const int qt = blockIdx.x & 15;
    const int b = bh >> 4, h = bh & 15;
    const int tid = threadIdx.x;
    const int w = tid >> 6;
    const int lane = tid & 63;
    const int c = lane & 15;        // fragment col: q index (and key row for A=K)
    const int quad = lane >> 4;

    const int q0 = qt * 64 + w * 16;
    bf16x8 qf0, qf1;                // B-operand: Q[q0+c][chunk*32 + quad*8 ..+7]
    {
        const u16* qrow = qkv + (size_t)(b * 1024 + q0 + c) * 3072 + h * 64;
        qf0 = *(const bf16x8*)(qrow + quad * 8);
        qf1 = *(const bf16x8*)(qrow + 32 + quad * 8);
    }
    f32x4 of[4];                    // O^T: d = dt*16 + quad*4 + r, q = c
#pragma unroll
    for (int dt = 0; dt < 4; dt++) of[dt] = (f32x4){0.f, 0.f, 0.f, 0.f};
    float mI = -1e30f, lI = 0.f;

    const int skey = tid >> 3;      // 0..31 (staging)
    const int sch  = tid & 7;       // dim chunk (staging)
    const int src0 = (((2 * quad) & 3) << 4) + c;       // P permute sources
    const int src1 = (((2 * quad + 1) & 3) << 4) + c;

#pragma unroll 1
    for (int kt = 0; kt < 1024; kt += 64) {
        __syncthreads();
#pragma unroll
        for (int p = 0; p < 2; p++) {
            const int key = skey + p * 32;
            const u16* krow = qkv + (size_t)(b * 1024 + kt + key) * 3072 + 1024
                              + h * 64 + sch * 8;
            uint4 kv = *(const uint4*)krow;
            *(uint4*)&sK[key * 72 + sch * 8] = kv;
            U4 vv; vv.u = *(const uint4*)(krow + 1024);
#pragma unroll
            for (int e = 0; e < 8; e++) sVt[(sch * 8 + e) * 72 + key] = vv.s[e];
        }
        __syncthreads();
#pragma unroll
        for (int ks = 0; ks < 64; ks += 32) {
            // ---- S^T: two 16-key tiles over 32 keys, full K=64 contraction
            bf16x8 k00 = *(const bf16x8*)&sK[(ks + c) * 72 + quad * 8];
            bf16x8 k01 = *(const bf16x8*)&sK[(ks + c) * 72 + 32 + quad * 8];
            bf16x8 k10 = *(const bf16x8*)&sK[(ks + 16 + c) * 72 + quad * 8];
            bf16x8 k11 = *(const bf16x8*)&sK[(ks + 16 + c) * 72 + 32 + quad * 8];
            f32x4 s0 = (f32x4){0.f, 0.f, 0.f, 0.f};
            f32x4 s1 = (f32x4){0.f, 0.f, 0.f, 0.f};
            s0 = __builtin_amdgcn_mfma_f32_16x16x32_bf16(k00, qf0, s0, 0, 0, 0);
            s0 = __builtin_amdgcn_mfma_f32_16x16x32_bf16(k01, qf1, s0, 0, 0, 0);
            s1 = __builtin_amdgcn_mfma_f32_16x16x32_bf16(k10, qf0, s1, 0, 0, 0);
            s1 = __builtin_amdgcn_mfma_f32_16x16x32_bf16(k11, qf1, s1, 0, 0, 0);
            // lane holds keys: s0[r] = key ks+4*quad+r, s1[r] = key ks+16+4*quad+r
            float sc[8];
#pragma unroll
            for (int r = 0; r < 4; r++) { sc[r] = s0[r] * 0.125f; sc[4 + r] = s1[r] * 0.125f; }
            // ---- online softmax (per q = c; reduce over quads)
            float tm = sc[0];
#pragma unroll
            for (int j = 1; j < 8; j++) tm = fmaxf(tm, sc[j]);
            tm = fmaxf(tm, __shfl_xor(tm, 16));
            tm = fmaxf(tm, __shfl_xor(tm, 32));
            const float mNew = fmaxf(mI, tm);
            const float alpha = __expf(mI - mNew);
            float p8[8];
            float psum = 0.f;
#pragma unroll
            for (int j = 0; j < 8; j++) { p8[j] = __expf(sc[j] - mNew); psum += p8[j]; }
            psum += __shfl_xor(psum, 16);
            psum += __shfl_xor(psum, 32);
            lI = lI * alpha + psum;
            mI = mNew;
#pragma unroll
            for (int dt = 0; dt < 4; dt++) {
#pragma unroll
                for (int r = 0; r < 4; r++) of[dt][r] *= alpha;
            }
            // ---- pack P to bf16 pairs, permute C-layout -> B-layout
            const unsigned int a0 = (unsigned)f2b(p8[0]) | ((unsigned)f2b(p8[1]) << 16);
            const unsigned int a1 = (unsigned)f2b(p8[2]) | ((unsigned)f2b(p8[3]) << 16);
            const unsigned int b0 = (unsigned)f2b(p8[4]) | ((unsigned)f2b(p8[5]) << 16);
            const unsigned int b1 = (unsigned)f2b(p8[6]) | ((unsigned)f2b(p8[7]) << 16);
            const unsigned int xa0 = (unsigned)__shfl((int)a0, src0);
            const unsigned int xb0 = (unsigned)__shfl((int)b0, src0);
            const unsigned int xa1 = (unsigned)__shfl((int)a1, src0);
            const unsigned int xb1 = (unsigned)__shfl((int)b1, src0);
            const unsigned int ya0 = (unsigned)__shfl((int)a0, src1);
            const unsigned int yb0 = (unsigned)__shfl((int)b0, src1);
            const unsigned int ya1 = (unsigned)__shfl((int)a1, src1);
            const unsigned int yb1 = (unsigned)__shfl((int)b1, src1);
            B8 pf;
            pf.w[0] = quad < 2 ? xa0 : xb0;   // keys 8*quad + {0,1}
            pf.w[1] = quad < 2 ? xa1 : xb1;   // keys 8*quad + {2,3}
            pf.w[2] = quad < 2 ? ya0 : yb0;   // keys 8*quad + {4,5}
            pf.w[3] = quad < 2 ? ya1 : yb1;   // keys 8*quad + {6,7}
            // ---- PV: O^T += V^T · P^T
#pragma unroll
            for (int dt = 0; dt < 4; dt++) {
                bf16x8 vf = *(const bf16x8*)&sVt[(dt * 16 + c) * 72 + ks + quad * 8];
                of[dt] = __builtin_amdgcn_mfma_f32_16x16x32_bf16(vf, pf.v, of[dt], 0, 0, 0);
            }
        }
    }
    const float inv = 1.f / lI;
    const size_t orow = (size_t)(b * 1024 + q0 + c) * 1024 + h * 64;
#pragma unroll
    for (int dt = 0; dt < 4; dt++) {
        U2 pk;
#pragma unroll
        for (int r = 0; r < 4; r++) pk.s[r] = f2b(of[dt][r] * inv);
        *(uint2*)(o_out + orow + dt * 16 + quad * 4) = pk.u;
    }
}

// ------------------------------------------------ launch
extern "C" void kernel_launch(void* const* d_in, const int* in_sizes, int n_in,
                              void* d_out, int out_size, void* d_ws, size_t ws_size,
                              hipStream_t stream) {
    (void)in_sizes; (void)n_in; (void)out_size; (void)ws_size;
    const void* x      = d_in[0];
    const void* cosb   = d_in[1];
    const void* sinb   = d_in[2];
    const void* c      = d_in[3];
    const void* w_ln1  = d_in[4];
    const void* w_ln2  = d_in[5];
    const void* w_qkv  = d_in[6];
    const void* w_attn = d_in[7];
    const void* w_mlp1 = d_in[8];
    const void* b_mlp1 = d_in[9];
    const void* w_mlp2 = d_in[10];
    const void* b_mlp2 = d_in[11];
    const void* w_ada  = d_in[12];
    const void* b_ada  = d_in[13];
    char* ws = (char*)d_ws;

    u16*   wT_qkv  = (u16*)(ws + 0);          // 3072x1024 bf16
    u16*   wT_attn = (u16*)(ws + 6291456);    // 1024x1024 bf16
    u16*   wT_mlp1 = (u16*)(ws + 8388608);    // 4096x1024 bf16
    u16*   wT_mlp2 = (u16*)(ws + 16777216);   // 1024x4096 bf16
    float* mod     = (float*)(ws + 25165824); // 4x6144 f32
    u16*   hbuf    = (u16*)(ws + 25264128);   // h -> o -> h2 (4096x1024 bf16)
    u16*   big     = (u16*)(ws + 33652736);   // qkv (4096x3072) -> m1 (4096x4096) bf16
    float* x2      = (float*)(ws + 67207168); // 4096x1024 f32
    int*   flag    = (int*)(ws + 83984384);   // dtype flag

    detect_dtype<<<1, 64, 0, stream>>>((const unsigned int*)w_ln1, flag);
    transpose_any<<<dim3(16 * 48), 256, 0, stream>>>(w_qkv, wT_qkv, 1024, 3072, flag);
    transpose_any<<<dim3(16 * 16), 256, 0, stream>>>(w_attn, wT_attn, 1024, 1024, flag);
    transpose_any<<<dim3(16 * 64), 256, 0, stream>>>(w_mlp1, wT_mlp1, 1024, 4096, flag);
    transpose_any<<<dim3(64 * 16), 256, 0, stream>>>(w_mlp2, wT_mlp2, 4096, 1024, flag);
    ada_kernel<<<96, 256, 0, stream>>>(c, w_ada, b_ada, mod, flag);
    ln_mod_kernel<<<4096, 256, 0, stream>>>(x, w_ln1, mod, 0, 1024, hbuf, flag, 0);
    gemm_bt<EPI_STORE><<<dim3(24, 32), 256, 0, stream>>>(
        hbuf, wT_qkv, big, 4096, 3072, 1024, nullptr, nullptr, nullptr, flag);
    rope_kernel<<<2048, 256, 0, stream>>>(big, cosb, sinb, flag);
    attn_mfma<<<1024, 256, 0, stream>>>(big, hbuf);
    gemm_bt<EPI_RES_GATE><<<dim3(8, 32), 256, 0, stream>>>(
        hbuf, wT_attn, x2, 4096, 1024, 1024, x, mod + 2048, nullptr, flag);
    ln_mod_kernel<<<4096, 256, 0, stream>>>(x2, w_ln2, mod, 3072, 4096, hbuf, flag, 1);
    gemm_bt<EPI_GELU_BIAS><<<dim3(32, 32), 256, 0, stream>>>(
        hbuf, wT_mlp1, big, 4096, 4096, 1024, nullptr, nullptr, b_mlp1, flag);
    gemm_bt<EPI_RES_GATE_BIAS><<<dim3(8, 32), 256, 0, stream>>>(
        big, wT_mlp2, (float*)d_out, 4096, 1024, 4096, x2, mod + 5120, b_mlp2, flag);
}

// Round 6
// 468.583 us; speedup vs baseline: 2.9135x; 1.2158x over previous
//
#include <hip/hip_runtime.h>
#include <stdint.h>

typedef unsigned short u16;
typedef __bf16 bf16x8 __attribute__((ext_vector_type(8)));
typedef float f32x4 __attribute__((ext_vector_type(4)));

#define MOD6  6144

__device__ __forceinline__ float b2f(unsigned int u) {
    union { unsigned int i; float f; } z; z.i = u << 16; return z.f;
}
__device__ __forceinline__ u16 f2b(float f) {
    union { float f; unsigned int i; } z; z.f = f;
    unsigned int i = z.i;
    return (u16)((i + 0x7fffu + ((i >> 16) & 1u)) >> 16);
}
union U4 { uint4 u; u16 s[8]; };
union U2 { uint2 u; u16 s[4]; };
union B8 { bf16x8 v; unsigned int w[4]; };

__device__ __forceinline__ float ldf(const void* p, size_t i, int isbf) {
    if (isbf) return b2f(((const u16*)p)[i]);
    return ((const float*)p)[i];
}
__device__ __forceinline__ void load4(const void* p, size_t i, int isbf, float* v) {
    if (isbf) {
        U2 t; t.u = *(const uint2*)((const u16*)p + i);
#pragma unroll
        for (int e = 0; e < 4; e++) v[e] = b2f(t.s[e]);
    } else {
        float4 f = *(const float4*)((const float*)p + i);
        v[0] = f.x; v[1] = f.y; v[2] = f.z; v[3] = f.w;
    }
}

// async global->LDS, 16B per lane. LDS dest must be wave-uniform base + lane*16.
__device__ __forceinline__ void gld16(u16* lds, const u16* g) {
    __builtin_amdgcn_global_load_lds(
        (__attribute__((address_space(1))) void*)(g),
        (__attribute__((address_space(3))) void*)(lds), 16, 0, 0);
}

// ------------------------------------------------ dtype detector
__global__ void detect_dtype(const unsigned int* __restrict__ w, int* __restrict__ flag) {
    if (threadIdx.x == 0 && blockIdx.x == 0)
        *flag = (w[0] == 0x3F803F80u) ? 1 : 0;
}

// ------------------------------------------------ transpose (K,N) ext -> bf16 (N,K)
__global__ void transpose_any(const void* __restrict__ in, u16* __restrict__ out,
                              int K, int N, const int* __restrict__ flag) {
    const int isbf = *flag;
    __shared__ u16 tile[64][66];
    const int ntn = N >> 6;
    const int k0 = (blockIdx.x / ntn) << 6;
    const int n0 = (blockIdx.x % ntn) << 6;
    const int tid = threadIdx.x;
    const int r = tid >> 3;          // 0..31
    const int c = (tid & 7) * 8;     // 0..56
#pragma unroll
    for (int rr = 0; rr < 64; rr += 32) {
        const size_t base = (size_t)(k0 + r + rr) * N + n0 + c;
        u16* t = &tile[r + rr][c];
        if (isbf) {
            U4 v; v.u = *(const uint4*)((const u16*)in + base);
#pragma unroll
            for (int e = 0; e < 8; e++) t[e] = v.s[e];
        } else {
            float4 a = *(const float4*)((const float*)in + base);
            float4 b = *(const float4*)((const float*)in + base + 4);
            t[0] = f2b(a.x); t[1] = f2b(a.y); t[2] = f2b(a.z); t[3] = f2b(a.w);
            t[4] = f2b(b.x); t[5] = f2b(b.y); t[6] = f2b(b.z); t[7] = f2b(b.w);
        }
    }
    __syncthreads();
#pragma unroll
    for (int rr = 0; rr < 64; rr += 32) {
        U4 v;
#pragma unroll
        for (int e = 0; e < 8; e++) v.s[e] = tile[c + e][r + rr];
        *(uint4*)&out[(size_t)(n0 + r + rr) * K + k0 + c] = v.u;
    }
}

// ------------------------------------------------ adaLN modulation, split-K
// stage 1: 8 k-slices of 128; 768 blocks; partials f32
__global__ void ada_partial(const void* __restrict__ c, const void* __restrict__ w_ada,
                            float* __restrict__ part, const int* __restrict__ flag) {
    const int isbf = *flag;
    const int g = blockIdx.x * 256 + threadIdx.x;   // 0..196607
    const int slice = g / 24576;                    // 0..7
    const int idx = g - slice * 24576;
    const int b = idx / MOD6, n = idx - (idx / MOD6) * MOD6;
    const int k0 = slice * 128;
    float acc = 0.f;
    if (isbf) {
        const u16* cr = (const u16*)c + b * 1024 + k0;
        const u16* wp = (const u16*)w_ada + (size_t)k0 * MOD6 + n;
#pragma unroll 8
        for (int k = 0; k < 128; k++)
            acc += b2f(cr[k]) * b2f(wp[(size_t)k * MOD6]);
    } else {
        const float* cr = (const float*)c + b * 1024 + k0;
        const float* wp = (const float*)w_ada + (size_t)k0 * MOD6 + n;
#pragma unroll 8
        for (int k = 0; k < 128; k++)
            acc += cr[k] * wp[(size_t)k * MOD6];
    }
    part[g] = acc;
}
// stage 2: reduce 8 partials + bias
__global__ void ada_reduce(const float* __restrict__ part, const void* __restrict__ b_ada,
                           float* __restrict__ mod, const int* __restrict__ flag) {
    const int g = blockIdx.x * 256 + threadIdx.x;   // 0..24575
    float acc = ldf(b_ada, g % MOD6, *flag);
#pragma unroll
    for (int s = 0; s < 8; s++) acc += part[s * 24576 + g];
    mod[g] = acc;
}

// ------------------------------------------------ LN + modulate -> bf16
__global__ void ln_mod_kernel(const void* __restrict__ x, const void* __restrict__ w,
                              const float* __restrict__ mod, int shift_off,
                              int scale_off, u16* __restrict__ out,
                              const int* __restrict__ flag, int x_is_f32) {
    const int isbf = *flag;
    const int xb = x_is_f32 ? 0 : isbf;
    const int tk = blockIdx.x;
    const int b = tk >> 10;
    const int tid = threadIdx.x;
    float v[4];
    load4(x, (size_t)tk * 1024 + tid * 4, xb, v);
    float s = v[0] + v[1] + v[2] + v[3];
    float ss = v[0]*v[0] + v[1]*v[1] + v[2]*v[2] + v[3]*v[3];
#pragma unroll
    for (int off = 1; off < 64; off <<= 1) {
        s  += __shfl_xor(s, off);
        ss += __shfl_xor(ss, off);
    }
    __shared__ float ls[4], lss[4];
    if ((tid & 63) == 0) { ls[tid >> 6] = s; lss[tid >> 6] = ss; }
    __syncthreads();
    s  = ls[0] + ls[1] + ls[2] + ls[3];
    ss = lss[0] + lss[1] + lss[2] + lss[3];
    const float mu  = s * (1.f / 1024.f);
    const float var = ss * (1.f / 1024.f) - mu * mu;
    const float rstd = rsqrtf(var + 1e-5f);
    float wv[4];
    load4(w, (size_t)tid * 4, isbf, wv);
    const float* mb = mod + (size_t)b * MOD6;
    U2 o;
#pragma unroll
    for (int e = 0; e < 4; e++) {
        const int col = tid * 4 + e;
        float n = (v[e] - mu) * rstd * wv[e];
        o.s[e] = f2b(n * (1.f + mb[scale_off + col]) + mb[shift_off + col]);
    }
    *(uint2*)(out + (size_t)tk * 1024 + tid * 4) = o.u;
}

// ------------------------------------------------ GEMM  C = A @ Bt^T (+epilogue)
// m97-style: global_load_lds width-16 staging, unpadded 128x32 LDS tiles,
// XOR-swizzled column chunks (4-way bank aliasing on fragment reads).
#define EPI_STORE 0
#define EPI_RES_GATE 1        // f32 out: res_ext(dual) + gate*v
#define EPI_GELU_BIAS 2       // bf16 out: gelu(v + bias_ext)
#define EPI_RES_GATE_BIAS 3   // f32 out (d_out): res_f32 + gate*(v + bias_ext)

template <int EPI>
__launch_bounds__(256, 2)
__global__ void gemm_bt(const u16* __restrict__ A, const u16* __restrict__ Bt,
                        void* __restrict__ Cv, int M, int N, int K,
                        const void* __restrict__ res, const float* __restrict__ gate,
                        const void* __restrict__ bias, const int* __restrict__ flag) {
    __shared__ __align__(16) u16 sA[128 * 32];
    __shared__ __align__(16) u16 sB[128 * 32];
    const int isbf = flag ? *flag : 0;
    const int tid = threadIdx.x;
    const int lane = tid & 63;
    const int w = tid >> 6;
    const int wm = w >> 1, wn = w & 1;
    const int c16 = lane & 15, quad = lane >> 4;
    const int m0 = blockIdx.y * 128, n0 = blockIdx.x * 128;

    // staging map: wave w, pass p stages rows [16*(w+4p), +16); lane: row l>>2, chunk l&3
    const int srow = lane >> 2;          // 0..15
    const int schunk = lane & 3;
    const int gchunk = schunk ^ (srow & 3);   // global-side swizzle

    const u16* gA = A + (size_t)m0 * K + 8 * gchunk;
    const u16* gB = Bt + (size_t)n0 * K + 8 * gchunk;
    const int cs = quad ^ (c16 & 3);     // fragment-read chunk (de-swizzle)

    f32x4 acc[4][4];
#pragma unroll
    for (int i = 0; i < 4; i++)
#pragma unroll
        for (int j = 0; j < 4; j++) acc[i][j] = (f32x4){0.f, 0.f, 0.f, 0.f};

#pragma unroll 1
    for (int kt = 0; kt < K; kt += 32) {
        __syncthreads();
#pragma unroll
        for (int p = 0; p < 2; p++) {
            const int r = 16 * (w + 4 * p) + srow;
            gld16(&sA[r * 32 + 8 * schunk], gA + (size_t)r * K + kt);
            gld16(&sB[r * 32 + 8 * schunk], gB + (size_t)r * K + kt);
        }
        __syncthreads();
        bf16x8 af[4], bfr[4];
#pragma unroll
        for (int i = 0; i < 4; i++)
            af[i] = *(const bf16x8*)&sA[(64 * wm + 16 * i + c16) * 32 + 8 * cs];
#pragma unroll
        for (int j = 0; j < 4; j++)
            bfr[j] = *(const bf16x8*)&sB[(64 * wn + 16 * j + c16) * 32 + 8 * cs];
#pragma unroll
        for (int i = 0; i < 4; i++)
#pragma unroll
            for (int j = 0; j < 4; j++)
                acc[i][j] = __builtin_amdgcn_mfma_f32_16x16x32_bf16(
                    af[i], bfr[j], acc[i][j], 0, 0, 0);
    }

#pragma unroll
    for (int i = 0; i < 4; i++) {
#pragma unroll
        for (int r = 0; r < 4; r++) {
            const int row = m0 + 64 * wm + 16 * i + 4 * quad + r;
            const int b = row >> 10;
#pragma unroll
            for (int j = 0; j < 4; j++) {
                const int col = n0 + 64 * wn + 16 * j + c16;
                float v = acc[i][j][r];
                if constexpr (EPI == EPI_GELU_BIAS) {
                    v += ldf(bias, col, isbf);
                    const float u = 0.7978845608f * (v + 0.044715f * v * v * v);
                    const float e = __expf(2.f * u);
                    const float t = 1.f - 2.f / (e + 1.f);   // tanh(u), inf-safe
                    v = 0.5f * v * (1.f + t);
                } else if constexpr (EPI == EPI_RES_GATE) {
                    v = ldf(res, (size_t)row * N + col, isbf)
                        + gate[(size_t)b * MOD6 + col] * v;
                } else if constexpr (EPI == EPI_RES_GATE_BIAS) {
                    v += ldf(bias, col, isbf);
                    v = ((const float*)res)[(size_t)row * N + col]
                        + gate[(size_t)b * MOD6 + col] * v;
                }
                if constexpr (EPI == EPI_RES_GATE || EPI == EPI_RES_GATE_BIAS) {
                    ((float*)Cv)[(size_t)row * N + col] = v;
                } else {
                    ((u16*)Cv)[(size_t)row * N + col] = f2b(v);
                }
            }
        }
    }
}

// ------------------------------------------------ RoPE in-place on qkv (bf16)
__global__ void rope_kernel(u16* __restrict__ qkv, const void* __restrict__ cosb,
                            const void* __restrict__ sinb, const int* __restrict__ flag) {
    const int isbf = *flag;
    const int g = blockIdx.x * 256 + threadIdx.x;  // 524288
    const int q8 = g & 7;
    const int h = (g >> 3) & 15;
    const int tk = g >> 7;
    const int s = tk & 1023;
    const int d = q8 * 4;
    u16* row = qkv + (size_t)tk * 3072;

    float c4[4], s4[4];
    load4(cosb, (size_t)s * 32 + d, isbf, c4);
    load4(sinb, (size_t)s * 32 + d, isbf, s4);

#pragma unroll
    for (int which = 0; which < 2; which++) {   // q then k
        u16* p1 = row + which * 1024 + h * 64 + d;
        u16* p2 = p1 + 32;
        U2 t1, t2;
        t1.u = *(const uint2*)p1;
        t2.u = *(const uint2*)p2;
        U2 o1, o2;
#pragma unroll
        for (int e = 0; e < 4; e++) {
            const float a = b2f(t1.s[e]), bb = b2f(t2.s[e]);
            o1.s[e] = f2b(a * c4[e] - bb * s4[e]);
            o2.s[e] = f2b(bb * c4[e] + a * s4[e]);
        }
        *(uint2*)p1 = o1.u;
        *(uint2*)p2 = o2.u;
    }
}

// ------------------------------------------------ MFMA flash attention
__launch_bounds__(256, 4)
__global__ void attn_mfma(const u16* __restrict__ qkv, u16* __restrict__ o_out) {
    __shared__ __align__(16) u16 sK[64 * 72];    // keys x dims, pad 72
    __shared__ __align__(16) u16 sVt[64 * 72];   // dims x keys, pad 72
    const int bh = blockIdx.x >> 4;
    const int qt = blockIdx.x & 15;
    const int b = bh >> 4, h = bh & 15;
    const int tid = threadIdx.x;
    const int w = tid >> 6;
    const int lane = tid & 63;
    const int c = lane & 15;
    const int quad = lane >> 4;

    const int q0 = qt * 64 + w * 16;
    bf16x8 qf0, qf1;
    {
        const u16* qrow = qkv + (size_t)(b * 1024 + q0 + c) * 3072 + h * 64;
        qf0 = *(const bf16x8*)(qrow + quad * 8);
        qf1 = *(const bf16x8*)(qrow + 32 + quad * 8);
    }
    f32x4 of[4];
#pragma unroll
    for (int dt = 0; dt < 4; dt++) of[dt] = (f32x4){0.f, 0.f, 0.f, 0.f};
    float mI = -1e30f, lI = 0.f;

    const int skey = tid >> 3;
    const int sch  = tid & 7;
    const int src0 = (((2 * quad) & 3) << 4) + c;
    const int src1 = (((2 * quad + 1) & 3) << 4) + c;

#pragma unroll 1
    for (int kt = 0; kt < 1024; kt += 64) {
        __syncthreads();
#pragma unroll
        for (int p = 0; p < 2; p++) {
            const int key = skey + p * 32;
            const u16* krow = qkv + (size_t)(b * 1024 + kt + key) * 3072 + 1024
                              + h * 64 + sch * 8;
            uint4 kv = *(const uint4*)krow;
            *(uint4*)&sK[key * 72 + sch * 8] = kv;
            U4 vv; vv.u = *(const uint4*)(krow + 1024);
#pragma unroll
            for (int e = 0; e < 8; e++) sVt[(sch * 8 + e) * 72 + key] = vv.s[e];
        }
        __syncthreads();
#pragma unroll
        for (int ks = 0; ks < 64; ks += 32) {
            bf16x8 k00 = *(const bf16x8*)&sK[(ks + c) * 72 + quad * 8];
            bf16x8 k01 = *(const bf16x8*)&sK[(ks + c) * 72 + 32 + quad * 8];
            bf16x8 k10 = *(const bf16x8*)&sK[(ks + 16 + c) * 72 + quad * 8];
            bf16x8 k11 = *(const bf16x8*)&sK[(ks + 16 + c) * 72 + 32 + quad * 8];
            f32x4 s0 = (f32x4){0.f, 0.f, 0.f, 0.f};
            f32x4 s1 = (f32x4){0.f, 0.f, 0.f, 0.f};
            s0 = __builtin_amdgcn_mfma_f32_16x16x32_bf16(k00, qf0, s0, 0, 0, 0);
            s0 = __builtin_amdgcn_mfma_f32_16x16x32_bf16(k01, qf1, s0, 0, 0, 0);
            s1 = __builtin_amdgcn_mfma_f32_16x16x32_bf16(k10, qf0, s1, 0, 0, 0);
            s1 = __builtin_amdgcn_mfma_f32_16x16x32_bf16(k11, qf1, s1, 0, 0, 0);
            float sc[8];
#pragma unroll
            for (int r = 0; r < 4; r++) { sc[r] = s0[r] * 0.125f; sc[4 + r] = s1[r] * 0.125f; }
            float tm = sc[0];
#pragma unroll
            for (int j = 1; j < 8; j++) tm = fmaxf(tm, sc[j]);
            tm = fmaxf(tm, __shfl_xor(tm, 16));
            tm = fmaxf(tm, __shfl_xor(tm, 32));
            const float mNew = fmaxf(mI, tm);
            const float alpha = __expf(mI - mNew);
            float p8[8];
            float psum = 0.f;
#pragma unroll
            for (int j = 0; j < 8; j++) { p8[j] = __expf(sc[j] - mNew); psum += p8[j]; }
            psum += __shfl_xor(psum, 16);
            psum += __shfl_xor(psum, 32);
            lI = lI * alpha + psum;
            mI = mNew;
#pragma unroll
            for (int dt = 0; dt < 4; dt++) {
#pragma unroll
                for (int r = 0; r < 4; r++) of[dt][r] *= alpha;
            }
            const unsigned int a0 = (unsigned)f2b(p8[0]) | ((unsigned)f2b(p8[1]) << 16);
            const unsigned int a1 = (unsigned)f2b(p8[2]) | ((unsigned)f2b(p8[3]) << 16);
            const unsigned int b0 = (unsigned)f2b(p8[4]) | ((unsigned)f2b(p8[5]) << 16);
            const unsigned int b1 = (unsigned)f2b(p8[6]) | ((unsigned)f2b(p8[7]) << 16);
            const unsigned int xa0 = (unsigned)__shfl((int)a0, src0);
            const unsigned int xb0 = (unsigned)__shfl((int)b0, src0);
            const unsigned int xa1 = (unsigned)__shfl((int)a1, src0);
            const unsigned int xb1 = (unsigned)__shfl((int)b1, src0);
            const unsigned int ya0 = (unsigned)__shfl((int)a0, src1);
            const unsigned int yb0 = (unsigned)__shfl((int)b0, src1);
            const unsigned int ya1 = (unsigned)__shfl((int)a1, src1);
            const unsigned int yb1 = (unsigned)__shfl((int)b1, src1);
            B8 pf;
            pf.w[0] = quad < 2 ? xa0 : xb0;
            pf.w[1] = quad < 2 ? xa1 : xb1;
            pf.w[2] = quad < 2 ? ya0 : yb0;
            pf.w[3] = quad < 2 ? ya1 : yb1;
#pragma unroll
            for (int dt = 0; dt < 4; dt++) {
                bf16x8 vf = *(const bf16x8*)&sVt[(dt * 16 + c) * 72 + ks + quad * 8];
                of[dt] = __builtin_amdgcn_mfma_f32_16x16x32_bf16(vf, pf.v, of[dt], 0, 0, 0);
            }
        }
    }
    const float inv = 1.f / lI;
    const size_t orow = (size_t)(b * 1024 + q0 + c) * 1024 + h * 64;
#pragma unroll
    for (int dt = 0; dt < 4; dt++) {
        U2 pk;
#pragma unroll
        for (int r = 0; r < 4; r++) pk.s[r] = f2b(of[dt][r] * inv);
        *(uint2*)(o_out + orow + dt * 16 + quad * 4) = pk.u;
    }
}

// ------------------------------------------------ launch
extern "C" void kernel_launch(void* const* d_in, const int* in_sizes, int n_in,
                              void* d_out, int out_size, void* d_ws, size_t ws_size,
                              hipStream_t stream) {
    (void)in_sizes; (void)n_in; (void)out_size; (void)ws_size;
    const void* x      = d_in[0];
    const void* cosb   = d_in[1];
    const void* sinb   = d_in[2];
    const void* c      = d_in[3];
    const void* w_ln1  = d_in[4];
    const void* w_ln2  = d_in[5];
    const void* w_qkv  = d_in[6];
    const void* w_attn = d_in[7];
    const void* w_mlp1 = d_in[8];
    const void* b_mlp1 = d_in[9];
    const void* w_mlp2 = d_in[10];
    const void* b_mlp2 = d_in[11];
    const void* w_ada  = d_in[12];
    const void* b_ada  = d_in[13];
    char* ws = (char*)d_ws;

    u16*   wT_qkv  = (u16*)(ws + 0);          // 3072x1024 bf16
    u16*   wT_attn = (u16*)(ws + 6291456);    // 1024x1024 bf16
    u16*   wT_mlp1 = (u16*)(ws + 8388608);    // 4096x1024 bf16
    u16*   wT_mlp2 = (u16*)(ws + 16777216);   // 1024x4096 bf16
    float* mod     = (float*)(ws + 25165824); // 4x6144 f32
    u16*   hbuf    = (u16*)(ws + 25264128);   // h -> o -> h2 (4096x1024 bf16)
    u16*   big     = (u16*)(ws + 33652736);   // qkv (4096x3072) -> m1 (4096x4096) bf16
    float* x2      = (float*)(ws + 67207168); // 4096x1024 f32
    int*   flag    = (int*)(ws + 83984384);   // dtype flag
    float* part    = (float*)big;             // ada partials (borrow big pre-qkv)

    detect_dtype<<<1, 64, 0, stream>>>((const unsigned int*)w_ln1, flag);
    transpose_any<<<dim3(16 * 48), 256, 0, stream>>>(w_qkv, wT_qkv, 1024, 3072, flag);
    transpose_any<<<dim3(16 * 16), 256, 0, stream>>>(w_attn, wT_attn, 1024, 1024, flag);
    transpose_any<<<dim3(16 * 64), 256, 0, stream>>>(w_mlp1, wT_mlp1, 1024, 4096, flag);
    transpose_any<<<dim3(64 * 16), 256, 0, stream>>>(w_mlp2, wT_mlp2, 4096, 1024, flag);
    ada_partial<<<768, 256, 0, stream>>>(c, w_ada, part, flag);
    ada_reduce<<<96, 256, 0, stream>>>(part, b_ada, mod, flag);
    ln_mod_kernel<<<4096, 256, 0, stream>>>(x, w_ln1, mod, 0, 1024, hbuf, flag, 0);
    gemm_bt<EPI_STORE><<<dim3(24, 32), 256, 0, stream>>>(
        hbuf, wT_qkv, big, 4096, 3072, 1024, nullptr, nullptr, nullptr, flag);
    rope_kernel<<<2048, 256, 0, stream>>>(big, cosb, sinb, flag);
    attn_mfma<<<1024, 256, 0, stream>>>(big, hbuf);
    gemm_bt<EPI_RES_GATE><<<dim3(8, 32), 256, 0, stream>>>(
        hbuf, wT_attn, x2, 4096, 1024, 1024, x, mod + 2048, nullptr, flag);
    ln_mod_kernel<<<4096, 256, 0, stream>>>(x2, w_ln2, mod, 3072, 4096, hbuf, flag, 1);
    gemm_bt<EPI_GELU_BIAS><<<dim3(32, 32), 256, 0, stream>>>(
        hbuf, wT_mlp1, big, 4096, 4096, 1024, nullptr, nullptr, b_mlp1, flag);
    gemm_bt<EPI_RES_GATE_BIAS><<<dim3(8, 32), 256, 0, stream>>>(
        big, wT_mlp2, (float*)d_out, 4096, 1024, 4096, x2, mod + 5120, b_mlp2, flag);
}